// Round 1
// baseline (4071.375 us; speedup 1.0000x reference)
//
#include <hip/hip_runtime.h>
#include <hip/hip_bf16.h>

// B=8, C=256, H=W=64, N=4096.
// Strategy: 1) project Q,K,V into workspace transposed [B,N,C] (fp32).
//           2) flash-style attention, 32 query rows per block, fp32 VALU.
// Workspace requirement: 3 * 8*4096*256 * 4B = 100.7 MB.

#define BATCH 8
#define CH    256
#define NPIX  4096

// ---------------- projection: oT[b,n,o] = sum_c w[o,c]*x[b,c,n] + bias[o] ---
#define PNT 64   // n-tile per block

__global__ __launch_bounds__(256) void proj_kernel(
    const float* __restrict__ x, const float* __restrict__ w,
    const float* __restrict__ bias, float* __restrict__ oT) {
  __shared__ __align__(16) float xs[32][PNT];   // 8 KB
  __shared__ float wsm[32][257];                // 32.9 KB, padded
  const int b  = blockIdx.x >> 6;        // 64 n-tiles of 64
  const int n0 = (blockIdx.x & 63) * PNT;
  const int t  = threadIdx.x;            // t == output channel o

  float acc[PNT];
  const float bv = bias[t];
#pragma unroll
  for (int i = 0; i < PNT; ++i) acc[i] = bv;

  const float* xb = x + (size_t)b * CH * NPIX + n0;

  for (int c0 = 0; c0 < CH; c0 += 32) {
    // stage x[b, c0..c0+31, n0..n0+63]
    for (int idx = t; idx < 32 * PNT; idx += 256) {
      int cc = idx >> 6, nn = idx & 63;
      xs[cc][nn] = xb[(size_t)(c0 + cc) * NPIX + nn];
    }
    // stage w[o, c0..c0+31] transposed -> wsm[cc][o]
    for (int idx = t; idx < 256 * 32; idx += 256) {
      int o = idx >> 5, cc = idx & 31;
      wsm[cc][o] = w[o * CH + c0 + cc];
    }
    __syncthreads();
#pragma unroll 1
    for (int cc = 0; cc < 32; ++cc) {
      float wv = wsm[cc][t];
#pragma unroll
      for (int nn = 0; nn < PNT; nn += 4) {
        float4 xv = *(const float4*)&xs[cc][nn];
        acc[nn]     += wv * xv.x;
        acc[nn + 1] += wv * xv.y;
        acc[nn + 2] += wv * xv.z;
        acc[nn + 3] += wv * xv.w;
      }
    }
    __syncthreads();
  }
  // write oT[b, n0+nn, t]  (coalesced: lanes span o)
  float* ob = oT + ((size_t)b * NPIX + n0) * CH + t;
#pragma unroll
  for (int nn = 0; nn < PNT; ++nn) ob[(size_t)nn * CH] = acc[nn];
}

// ---------------- attention --------------------------------------------------
#define QT 32
#define KT 32
#define STR 260          // padded float stride for q/k/v LDS tiles
#define ATHREADS 512

__global__ __launch_bounds__(ATHREADS) void attn_kernel(
    const float* __restrict__ qT, const float* __restrict__ kT,
    const float* __restrict__ vT, float* __restrict__ out) {
  __shared__ __align__(16) float qs[QT][STR];     // 33.3 KB
  __shared__ __align__(16) float ks[KT][STR];     // 33.3 KB
  __shared__ __align__(16) float vs[KT][STR];     // 33.3 KB
  __shared__ float sbuf[QT][KT + 1];              // 4.2 KB (stride 33)
  __shared__ float mrow[QT], lrow[QT], srow[QT];

  const int b  = blockIdx.x >> 7;          // 128 q-tiles per batch
  const int i0 = (blockIdx.x & 127) * QT;
  const int t  = threadIdx.x;

  // load Q tile (QT x CH)
  const float* qbase = qT + ((size_t)b * NPIX + i0) * CH;
  for (int idx = t; idx < QT * CH / 4; idx += ATHREADS) {
    int r = idx / (CH / 4), c4 = idx % (CH / 4);
    float4 v = ((const float4*)qbase)[idx];
    *(float4*)&qs[r][c4 * 4] = v;
  }
  if (t < QT) { mrow[t] = -1e30f; lrow[t] = 0.f; }

  // accumulator ownership: row rr = t&31, channels c0..c0+15 with c0=(t>>5)*16
  const int rr = t & 31;
  const int c0 = (t >> 5) * 16;
  float acc[16];
#pragma unroll
  for (int i = 0; i < 16; ++i) acc[i] = 0.f;
  __syncthreads();

  for (int j0 = 0; j0 < NPIX; j0 += KT) {
    // stage K,V tiles (KT x CH each)
    const float* kbase = kT + ((size_t)b * NPIX + j0) * CH;
    const float* vbase = vT + ((size_t)b * NPIX + j0) * CH;
    for (int idx = t; idx < KT * CH / 4; idx += ATHREADS) {
      int r = idx / (CH / 4), c4 = idx % (CH / 4);
      *(float4*)&ks[r][c4 * 4] = ((const float4*)kbase)[idx];
      *(float4*)&vs[r][c4 * 4] = ((const float4*)vbase)[idx];
    }
    __syncthreads();

    // scores: 32x32 dots of length 256; thread -> (row=t&31, j=t>>5 and +16)
    {
      const int row = t & 31;
      const int jA = t >> 5;        // 0..15
      const int jB = jA + 16;
      float s0 = 0.f, s1 = 0.f;
#pragma unroll 8
      for (int c = 0; c < CH; c += 4) {
        float4 qv = *(const float4*)&qs[row][c];
        float4 ka = *(const float4*)&ks[jA][c];
        float4 kb = *(const float4*)&ks[jB][c];
        s0 += qv.x * ka.x + qv.y * ka.y + qv.z * ka.z + qv.w * ka.w;
        s1 += qv.x * kb.x + qv.y * kb.y + qv.z * kb.z + qv.w * kb.w;
      }
      sbuf[row][jA] = s0;
      sbuf[row][jB] = s1;
    }
    __syncthreads();

    // online softmax update; thread -> (r=t>>4, 16 lanes per row)
    {
      const int r = t >> 4;
      const int l16 = t & 15;
      float s0 = sbuf[r][l16];
      float s1 = sbuf[r][l16 + 16];
      float mx = fmaxf(s0, s1);
#pragma unroll
      for (int off = 1; off < 16; off <<= 1) mx = fmaxf(mx, __shfl_xor(mx, off));
      float mold = mrow[r];
      float mnew = fmaxf(mold, mx);
      float p0 = __expf(s0 - mnew);
      float p1 = __expf(s1 - mnew);
      float ps = p0 + p1;
#pragma unroll
      for (int off = 1; off < 16; off <<= 1) ps += __shfl_xor(ps, off);
      if (l16 == 0) {
        float scale = __expf(mold - mnew);
        lrow[r] = lrow[r] * scale + ps;
        mrow[r] = mnew;
        srow[r] = scale;
      }
      sbuf[r][l16] = p0;
      sbuf[r][l16 + 16] = p1;
    }
    __syncthreads();

    // PV: acc[rr][c0..c0+15] += sum_j p[rr][j] * vs[j][c0..]
    {
      const float scale = srow[rr];
#pragma unroll
      for (int i = 0; i < 16; ++i) acc[i] *= scale;
#pragma unroll 4
      for (int j = 0; j < KT; ++j) {
        float p = sbuf[rr][j];
#pragma unroll
        for (int cc = 0; cc < 16; cc += 4) {
          float4 vv = *(const float4*)&vs[j][c0 + cc];
          acc[cc]     += p * vv.x;
          acc[cc + 1] += p * vv.y;
          acc[cc + 2] += p * vv.z;
          acc[cc + 3] += p * vv.w;
        }
      }
    }
    __syncthreads();   // before next tile overwrites ks/vs/sbuf
  }

  // finalize: out[b, c, i] = acc / l
  const float linv = 1.0f / lrow[rr];
#pragma unroll
  for (int i = 0; i < 16; ++i) {
    out[((size_t)b * CH + (c0 + i)) * NPIX + i0 + rr] = acc[i] * linv;
  }
}

extern "C" void kernel_launch(void* const* d_in, const int* in_sizes, int n_in,
                              void* d_out, int out_size, void* d_ws, size_t ws_size,
                              hipStream_t stream) {
  const float* x  = (const float*)d_in[0];
  const float* wq = (const float*)d_in[1];
  const float* bq = (const float*)d_in[2];
  const float* wk = (const float*)d_in[3];
  const float* bk = (const float*)d_in[4];
  const float* wv = (const float*)d_in[5];
  const float* bv = (const float*)d_in[6];
  float* out = (float*)d_out;

  const size_t per = (size_t)BATCH * NPIX * CH;   // 8.4M floats
  float* qT = (float*)d_ws;
  float* kT = qT + per;
  float* vT = kT + per;

  dim3 pgrid(BATCH * (NPIX / PNT));   // 512 blocks
  proj_kernel<<<pgrid, 256, 0, stream>>>(x, wq, bq, qT);
  proj_kernel<<<pgrid, 256, 0, stream>>>(x, wk, bk, kT);
  proj_kernel<<<pgrid, 256, 0, stream>>>(x, wv, bv, vT);

  attn_kernel<<<dim3(BATCH * (NPIX / QT)), ATHREADS, 0, stream>>>(qT, kT, vT, out);
}

// Round 2
// 1045.117 us; speedup vs baseline: 3.8956x; 3.8956x over previous
//
#include <hip/hip_runtime.h>
#include <hip/hip_bf16.h>

// B=8, C=256, H=W=64, N=4096.
// v2: bf16 MFMA flash attention. Q,K hi/lo-split bf16 (3-pass exact-ish scores),
//     V/P single bf16. fp32 VALU projections write bf16 workspace.

#define BATCH 8
#define CH    256
#define NPIX  4096

typedef unsigned short ushort;
typedef __attribute__((ext_vector_type(8))) short short8;
typedef __attribute__((ext_vector_type(4))) float f32x4;

__device__ __forceinline__ ushort f2bf(float f) {
  unsigned u = __float_as_uint(f);
  unsigned r = (u + 0x7FFFu + ((u >> 16) & 1u)) >> 16;
  return (ushort)r;
}
__device__ __forceinline__ float bf2f(ushort h) {
  return __uint_as_float(((unsigned)h) << 16);
}

// ---------------- projection (fp32 compute): q,k -> [B,N,C] hi/lo bf16 -------
#define PNT 64

__global__ __launch_bounds__(256) void proj_qk(
    const float* __restrict__ x, const float* __restrict__ w,
    const float* __restrict__ bias, short* __restrict__ oh, short* __restrict__ ol) {
  __shared__ __align__(16) float xs[32][PNT];
  __shared__ float wsm[32][257];
  const int b  = blockIdx.x >> 6;
  const int n0 = (blockIdx.x & 63) * PNT;
  const int t  = threadIdx.x;

  float acc[PNT];
  const float bv = bias[t];
#pragma unroll
  for (int i = 0; i < PNT; ++i) acc[i] = bv;

  const float* xb = x + (size_t)b * CH * NPIX + n0;
  for (int c0 = 0; c0 < CH; c0 += 32) {
    for (int idx = t; idx < 32 * PNT; idx += 256) {
      int cc = idx >> 6, nn = idx & 63;
      xs[cc][nn] = xb[(size_t)(c0 + cc) * NPIX + nn];
    }
    for (int idx = t; idx < 256 * 32; idx += 256) {
      int o = idx >> 5, cc = idx & 31;
      wsm[cc][o] = w[o * CH + c0 + cc];
    }
    __syncthreads();
#pragma unroll 1
    for (int cc = 0; cc < 32; ++cc) {
      float wv = wsm[cc][t];
#pragma unroll
      for (int nn = 0; nn < PNT; nn += 4) {
        float4 xv = *(const float4*)&xs[cc][nn];
        acc[nn]     += wv * xv.x;
        acc[nn + 1] += wv * xv.y;
        acc[nn + 2] += wv * xv.z;
        acc[nn + 3] += wv * xv.w;
      }
    }
    __syncthreads();
  }
  short* ohb = oh + ((size_t)b * NPIX + n0) * CH + t;
  short* olb = ol + ((size_t)b * NPIX + n0) * CH + t;
#pragma unroll
  for (int nn = 0; nn < PNT; ++nn) {
    float vv = acc[nn];
    ushort h = f2bf(vv);
    float hf = bf2f(h);
    ushort lo = f2bf(vv - hf);
    ohb[(size_t)nn * CH] = (short)h;
    olb[(size_t)nn * CH] = (short)lo;
  }
}

// ---------------- projection for V: [B,C,N] bf16 ----------------------------
__global__ __launch_bounds__(256) void proj_v(
    const float* __restrict__ x, const float* __restrict__ w,
    const float* __restrict__ bias, short* __restrict__ ov) {
  __shared__ __align__(16) float xs[32][PNT];
  __shared__ float wsm[32][257];
  const int b  = blockIdx.x >> 6;
  const int n0 = (blockIdx.x & 63) * PNT;
  const int t  = threadIdx.x;

  float acc[PNT];
  const float bv = bias[t];
#pragma unroll
  for (int i = 0; i < PNT; ++i) acc[i] = bv;

  const float* xb = x + (size_t)b * CH * NPIX + n0;
  for (int c0 = 0; c0 < CH; c0 += 32) {
    for (int idx = t; idx < 32 * PNT; idx += 256) {
      int cc = idx >> 6, nn = idx & 63;
      xs[cc][nn] = xb[(size_t)(c0 + cc) * NPIX + nn];
    }
    for (int idx = t; idx < 256 * 32; idx += 256) {
      int o = idx >> 5, cc = idx & 31;
      wsm[cc][o] = w[o * CH + c0 + cc];
    }
    __syncthreads();
#pragma unroll 1
    for (int cc = 0; cc < 32; ++cc) {
      float wv = wsm[cc][t];
#pragma unroll
      for (int nn = 0; nn < PNT; nn += 4) {
        float4 xv = *(const float4*)&xs[cc][nn];
        acc[nn]     += wv * xv.x;
        acc[nn + 1] += wv * xv.y;
        acc[nn + 2] += wv * xv.z;
        acc[nn + 3] += wv * xv.w;
      }
    }
    __syncthreads();
  }
  // thread t = channel, 64 contiguous pixels -> short8 stores
  short* ob = ov + ((size_t)b * CH + t) * NPIX + n0;
#pragma unroll
  for (int g = 0; g < 8; ++g) {
    short8 pk;
#pragma unroll
    for (int e = 0; e < 8; ++e) pk[e] = (short)f2bf(acc[g * 8 + e]);
    *(short8*)(ob + g * 8) = pk;
  }
}

// ---------------- attention (bf16 MFMA flash) -------------------------------
#define QBLK 64
#define KBLK 32

__global__ __launch_bounds__(256) void attn_kernel(
    const short* __restrict__ qh, const short* __restrict__ ql,
    const short* __restrict__ kh, const short* __restrict__ kl,
    const short* __restrict__ vb, float* __restrict__ out) {
  __shared__ __align__(16) short khs[KBLK * CH];     // 16 KB, XOR-swizzled
  __shared__ __align__(16) short kls[KBLK * CH];     // 16 KB, XOR-swizzled
  __shared__ __align__(16) short vs[CH][40];         // 20 KB, padded
  __shared__ __align__(16) short ps[4][16][40];      // 5 KB, padded

  // XCD remap: 512 blocks, each XCD gets one batch (its 6MB K/V stays L2-hot)
  const int phys = blockIdx.x;
  const int lid  = (phys & 7) * 64 + (phys >> 3);
  const int b  = lid >> 6;
  const int i0 = (lid & 63) * QBLK;

  const int tid = threadIdx.x;
  const int w = tid >> 6, l = tid & 63;
  const int l15 = l & 15, q4 = l >> 4;
  const int cbase = q4 * 8;          // 8-elem K-chunk base within fragments

  // ---- preload Q fragments (A-layout: row=l&15, k=(l>>4)*8+e, contiguous) ---
  short8 qfh[8], qfl[8];
  {
    const size_t qrow = (size_t)b * NPIX + i0 + w * 16 + l15;
    const short* ph = qh + qrow * CH + cbase;
    const short* pl = ql + qrow * CH + cbase;
#pragma unroll
    for (int kc = 0; kc < 8; ++kc) {
      qfh[kc] = *(const short8*)(ph + kc * 32);
      qfl[kc] = *(const short8*)(pl + kc * 32);
    }
  }

  f32x4 o[16];
#pragma unroll
  for (int i = 0; i < 16; ++i) o[i] = (f32x4){0.f, 0.f, 0.f, 0.f};
  float m_r[4] = {-1e30f, -1e30f, -1e30f, -1e30f};
  float l_r[4] = {0.f, 0.f, 0.f, 0.f};

  // staging mapping
  const int sr = tid >> 3;            // K row 0..31
  const int sc = (tid & 7) * 32;      // col start (shorts)
  const short* gkh = kh + (size_t)b * NPIX * CH;
  const short* gkl = kl + (size_t)b * NPIX * CH;
  const short* gv  = vb + ((size_t)b * CH + tid) * NPIX;

#pragma unroll 1
  for (int j0 = 0; j0 < NPIX; j0 += KBLK) {
    __syncthreads();
    // ---- stage K hi/lo (swizzled) and V (padded) ----
    {
      const short* sK = gkh + (size_t)(j0 + sr) * CH + sc;
      const short* sL = gkl + (size_t)(j0 + sr) * CH + sc;
#pragma unroll
      for (int s2 = 0; s2 < 4; ++s2) {
        short8 a  = *(const short8*)(sK + s2 * 8);
        short8 c2 = *(const short8*)(sL + s2 * 8);
        int byte = sr * 512 + (sc + s2 * 8) * 2;
        byte ^= (sr & 7) << 4;
        *(short8*)((char*)khs + byte) = a;
        *(short8*)((char*)kls + byte) = c2;
      }
      const short* sV = gv + j0;
#pragma unroll
      for (int s2 = 0; s2 < 4; ++s2) {
        short8 a = *(const short8*)(sV + s2 * 8);
        *(short8*)&vs[tid][s2 * 8] = a;
      }
    }
    __syncthreads();

    // ---- QK^T: S[16 x 32] per wave, hi/lo 3-pass ----
    f32x4 s0 = {0.f, 0.f, 0.f, 0.f}, s1 = {0.f, 0.f, 0.f, 0.f};
#pragma unroll
    for (int kc = 0; kc < 8; ++kc) {
      int byte0 = l15 * 512 + (kc * 32 + cbase) * 2;
      byte0 ^= (l15 & 7) << 4;
      int byte1 = (l15 + 16) * 512 + (kc * 32 + cbase) * 2;
      byte1 ^= (l15 & 7) << 4;   // (row+16)&7 == row&7
      short8 bh0 = *(const short8*)((const char*)khs + byte0);
      short8 bh1 = *(const short8*)((const char*)khs + byte1);
      short8 bl0 = *(const short8*)((const char*)kls + byte0);
      short8 bl1 = *(const short8*)((const char*)kls + byte1);
      s0 = __builtin_amdgcn_mfma_f32_16x16x32_bf16(qfh[kc], bh0, s0, 0, 0, 0);
      s1 = __builtin_amdgcn_mfma_f32_16x16x32_bf16(qfh[kc], bh1, s1, 0, 0, 0);
      s0 = __builtin_amdgcn_mfma_f32_16x16x32_bf16(qfl[kc], bh0, s0, 0, 0, 0);
      s1 = __builtin_amdgcn_mfma_f32_16x16x32_bf16(qfl[kc], bh1, s1, 0, 0, 0);
      s0 = __builtin_amdgcn_mfma_f32_16x16x32_bf16(qfh[kc], bl0, s0, 0, 0, 0);
      s1 = __builtin_amdgcn_mfma_f32_16x16x32_bf16(qfh[kc], bl1, s1, 0, 0, 0);
    }

    // ---- online softmax (rows (l>>4)*4+r, cols l&15 / l&15+16) ----
    float scale[4], p0[4], p1[4];
#pragma unroll
    for (int r = 0; r < 4; ++r) {
      float a0 = s0[r], a1 = s1[r];
      float tm = fmaxf(a0, a1);
      tm = fmaxf(tm, __shfl_xor(tm, 1));
      tm = fmaxf(tm, __shfl_xor(tm, 2));
      tm = fmaxf(tm, __shfl_xor(tm, 4));
      tm = fmaxf(tm, __shfl_xor(tm, 8));
      if (tm > m_r[r] + 8.f) {        // T13 defer-rescale
        scale[r] = __expf(m_r[r] - tm);
        m_r[r] = tm;
      } else {
        scale[r] = 1.f;
      }
      p0[r] = __expf(a0 - m_r[r]);
      p1[r] = __expf(a1 - m_r[r]);
      float psum = p0[r] + p1[r];
      psum += __shfl_xor(psum, 1);
      psum += __shfl_xor(psum, 2);
      psum += __shfl_xor(psum, 4);
      psum += __shfl_xor(psum, 8);
      l_r[r] = l_r[r] * scale[r] + psum;
    }
    if (scale[0] != 1.f || scale[1] != 1.f || scale[2] != 1.f || scale[3] != 1.f) {
#pragma unroll
      for (int nt = 0; nt < 16; ++nt) {
        o[nt][0] *= scale[0];
        o[nt][1] *= scale[1];
        o[nt][2] *= scale[2];
        o[nt][3] *= scale[3];
      }
    }

    // ---- P -> LDS (bf16), then PV ----
#pragma unroll
    for (int r = 0; r < 4; ++r) {
      ps[w][q4 * 4 + r][l15]      = (short)f2bf(p0[r]);
      ps[w][q4 * 4 + r][l15 + 16] = (short)f2bf(p1[r]);
    }
    short8 pa = *(const short8*)&ps[w][l15][cbase];
#pragma unroll
    for (int nt = 0; nt < 16; ++nt) {
      short8 vv = *(const short8*)&vs[nt * 16 + l15][cbase];
      o[nt] = __builtin_amdgcn_mfma_f32_16x16x32_bf16(pa, vv, o[nt], 0, 0, 0);
    }
  }

  // ---- epilogue: out[b, c, i] = o / l ----
  float inv[4];
#pragma unroll
  for (int r = 0; r < 4; ++r) inv[r] = 1.f / l_r[r];
  float* ob = out + (size_t)b * CH * NPIX + i0 + w * 16;
#pragma unroll
  for (int nt = 0; nt < 16; ++nt) {
    const int c = nt * 16 + l15;
#pragma unroll
    for (int r = 0; r < 4; ++r)
      ob[(size_t)c * NPIX + q4 * 4 + r] = o[nt][r] * inv[r];
  }
}

extern "C" void kernel_launch(void* const* d_in, const int* in_sizes, int n_in,
                              void* d_out, int out_size, void* d_ws, size_t ws_size,
                              hipStream_t stream) {
  const float* x  = (const float*)d_in[0];
  const float* wq = (const float*)d_in[1];
  const float* bq = (const float*)d_in[2];
  const float* wk = (const float*)d_in[3];
  const float* bk = (const float*)d_in[4];
  const float* wv = (const float*)d_in[5];
  const float* bv = (const float*)d_in[6];
  float* out = (float*)d_out;

  const size_t per = (size_t)BATCH * NPIX * CH;   // 8.4M elems
  short* qh = (short*)d_ws;
  short* ql = qh + per;
  short* kh = ql + per;
  short* kl = kh + per;
  short* vb = kl + per;   // total 5*16.8MB = 84MB

  dim3 pgrid(BATCH * (NPIX / PNT));   // 512 blocks
  proj_qk<<<pgrid, 256, 0, stream>>>(x, wq, bq, qh, ql);
  proj_qk<<<pgrid, 256, 0, stream>>>(x, wk, bk, kh, kl);
  proj_v <<<pgrid, 256, 0, stream>>>(x, wv, bv, vb);

  attn_kernel<<<dim3(BATCH * (NPIX / QBLK)), 256, 0, stream>>>(qh, ql, kh, kl, vb, out);
}

// Round 3
// 826.817 us; speedup vs baseline: 4.9242x; 1.2640x over previous
//
#include <hip/hip_runtime.h>
#include <hip/hip_bf16.h>

// B=8, C=256, H=W=64, N=4096.
// v3: conflict-free staging writes + T14 reg-prefetch + ones-MFMA row sums
//     + threads-own-pixels fused projection with pre-transposed weights.

#define BATCH 8
#define CH    256
#define NPIX  4096

typedef unsigned short ushort;
typedef __attribute__((ext_vector_type(8))) short short8;
typedef __attribute__((ext_vector_type(4))) float f32x4;

__device__ __forceinline__ ushort f2bf(float f) {
  unsigned u = __float_as_uint(f);
  unsigned r = (u + 0x7FFFu + ((u >> 16) & 1u)) >> 16;
  return (ushort)r;
}
__device__ __forceinline__ float bf2f(ushort h) {
  return __uint_as_float(((unsigned)h) << 16);
}

// ---------------- weight transpose: wT[c][o] = w[o][c] ----------------------
__global__ __launch_bounds__(256) void transpose_w(
    const float* __restrict__ wq, const float* __restrict__ wk,
    const float* __restrict__ wv, float* __restrict__ wTq,
    float* __restrict__ wTk, float* __restrict__ wTv) {
  __shared__ float s[64][65];
  const int which = blockIdx.z;
  const float* w = which == 0 ? wq : which == 1 ? wk : wv;
  float* wT      = which == 0 ? wTq : which == 1 ? wTk : wTv;
  const int r0 = blockIdx.x * 64, c0 = blockIdx.y * 64;
  const int t = threadIdx.x;
  for (int idx = t; idx < 4096; idx += 256) {
    int r = idx >> 6, c = idx & 63;
    s[r][c] = w[(r0 + r) * 256 + c0 + c];
  }
  __syncthreads();
  for (int idx = t; idx < 4096; idx += 256) {
    int c = idx >> 6, r = idx & 63;
    wT[(c0 + c) * 256 + r0 + r] = s[r][c];
  }
}

// ---------------- fused projection (threads own pixels) ---------------------
// grid 512 = 8 b x 16 ntile x 4 oquarter; block 256 threads (one pixel each).
// q,k -> [B,N,C] hi/lo bf16 ; v -> [B,C,N] bf16.
__global__ __launch_bounds__(256) void proj_fused(
    const float* __restrict__ x,
    const float* __restrict__ wTq, const float* __restrict__ bq,
    const float* __restrict__ wTk, const float* __restrict__ bk,
    const float* __restrict__ wTv, const float* __restrict__ bv,
    short* __restrict__ qh, short* __restrict__ ql,
    short* __restrict__ kh, short* __restrict__ kl,
    short* __restrict__ vbuf) {
  __shared__ __align__(16) float xs[64][256];   // 64 KB
  const int gid = blockIdx.x;
  const int b = gid >> 6;
  const int ntile = (gid >> 2) & 15;
  const int ob = (gid & 3) * 64;
  const int n0 = ntile * 256;
  const int t = threadIdx.x;

#pragma unroll 1
  for (int pass = 0; pass < 3; ++pass) {
    const float* wT   = pass == 0 ? wTq : pass == 1 ? wTk : wTv;
    const float* bias = pass == 0 ? bq  : pass == 1 ? bk  : bv;
    float acc[64];
#pragma unroll
    for (int o = 0; o < 64; ++o) acc[o] = bias[ob + o];

#pragma unroll 1
    for (int cs = 0; cs < 256; cs += 64) {
      __syncthreads();
      for (int idx = t; idx < 64 * 64; idx += 256) {
        int r = idx >> 6, c4 = idx & 63;
        *(float4*)&xs[r][c4 * 4] =
            *(const float4*)&x[((size_t)b * CH + cs + r) * NPIX + n0 + c4 * 4];
      }
      __syncthreads();
#pragma unroll 2
      for (int cc = 0; cc < 64; ++cc) {
        const float xv = xs[cc][t];
        const float* __restrict__ wrow = wT + (cs + cc) * 256 + ob;
#pragma unroll
        for (int o = 0; o < 64; ++o) acc[o] += wrow[o] * xv;
      }
    }

    if (pass < 2) {
      short* oph = (pass == 0 ? qh : kh) + ((size_t)b * NPIX + n0 + t) * CH + ob;
      short* opl = (pass == 0 ? ql : kl) + ((size_t)b * NPIX + n0 + t) * CH + ob;
#pragma unroll
      for (int g = 0; g < 8; ++g) {
        short8 ph, pl;
#pragma unroll
        for (int e = 0; e < 8; ++e) {
          float vv = acc[g * 8 + e];
          ushort hh = f2bf(vv);
          ph[e] = (short)hh;
          pl[e] = (short)f2bf(vv - bf2f(hh));
        }
        *(short8*)(oph + g * 8) = ph;
        *(short8*)(opl + g * 8) = pl;
      }
    } else {
#pragma unroll 1
      for (int o = 0; o < 64; ++o) {
        vbuf[((size_t)b * CH + ob + o) * NPIX + n0 + t] = (short)f2bf(acc[o]);
      }
    }
  }
}

// ---------------- attention (bf16 MFMA flash) -------------------------------
#define QBLK 64
#define KBLK 32

__global__ __launch_bounds__(256, 2) void attn_kernel(
    const short* __restrict__ qh, const short* __restrict__ ql,
    const short* __restrict__ kh, const short* __restrict__ kl,
    const short* __restrict__ vb, float* __restrict__ out) {
  __shared__ __align__(16) short khs[KBLK * CH];     // 16 KB, XOR-swizzled
  __shared__ __align__(16) short kls[KBLK * CH];     // 16 KB, XOR-swizzled
  __shared__ __align__(16) short vs[CH][40];         // 20 KB, padded
  __shared__ __align__(16) short ps[4][16][40];      // 5 KB, padded

  // XCD remap: each XCD owns one batch (K/V L2-resident)
  const int phys = blockIdx.x;
  const int lid  = (phys & 7) * 64 + (phys >> 3);
  const int b  = lid >> 6;
  const int i0 = (lid & 63) * QBLK;

  const int tid = threadIdx.x;
  const int w = tid >> 6, l = tid & 63;
  const int l15 = l & 15, q4 = l >> 4;
  const int cbase = q4 * 8;

  // ---- preload Q fragments ----
  short8 qfh[8], qfl[8];
  {
    const size_t qrow = (size_t)b * NPIX + i0 + w * 16 + l15;
    const short* ph = qh + qrow * CH + cbase;
    const short* pl = ql + qrow * CH + cbase;
#pragma unroll
    for (int kc = 0; kc < 8; ++kc) {
      qfh[kc] = *(const short8*)(ph + kc * 32);
      qfl[kc] = *(const short8*)(pl + kc * 32);
    }
  }

  f32x4 o[16];
#pragma unroll
  for (int i = 0; i < 16; ++i) o[i] = (f32x4){0.f, 0.f, 0.f, 0.f};
  f32x4 o_l = (f32x4){0.f, 0.f, 0.f, 0.f};        // row sums via ones-MFMA
  float m_r[4] = {-1e30f, -1e30f, -1e30f, -1e30f};

  const short8 onesf = (short8){0x3F80, 0x3F80, 0x3F80, 0x3F80,
                                0x3F80, 0x3F80, 0x3F80, 0x3F80};

  // staging mapping (conflict-free writes):
  // K: row = w*8 + (l&7), chunk(16B) = (l>>3) + 8*s   (s=0..3)
  // V: ch  = s*64 + w*16 + (l>>2), j-chunk = l&3
  const int krow = w * 8 + (l & 7);
  const int kcb  = l >> 3;
  const short* gkh = kh + (size_t)b * NPIX * CH;
  const short* gkl = kl + (size_t)b * NPIX * CH;
  const short* gv  = vb + (size_t)b * CH * NPIX;

  short8 rkh[4], rkl[4], rv[4];
  // prologue: load tile 0
#pragma unroll
  for (int s = 0; s < 4; ++s) {
    const size_t ko = (size_t)krow * CH + (size_t)(kcb + 8 * s) * 8;
    rkh[s] = *(const short8*)(gkh + ko);
    rkl[s] = *(const short8*)(gkl + ko);
    rv[s]  = *(const short8*)(gv + (size_t)(s * 64 + w * 16 + (l >> 2)) * NPIX + (l & 3) * 8);
  }

#pragma unroll 1
  for (int j0 = 0; j0 < NPIX; j0 += KBLK) {
    __syncthreads();   // previous tile's readers done
    // ---- write staged regs -> LDS ----
#pragma unroll
    for (int s = 0; s < 4; ++s) {
      int wb = (krow * 512 + (kcb + 8 * s) * 16) ^ ((krow & 7) << 4);
      *(short8*)((char*)khs + wb) = rkh[s];
      *(short8*)((char*)kls + wb) = rkl[s];
      *(short8*)&vs[s * 64 + w * 16 + (l >> 2)][(l & 3) * 8] = rv[s];
    }
    __syncthreads();   // tile ready

    // ---- T14 prefetch next tile into regs (flies during compute) ----
    const int jn = j0 + KBLK;
    if (jn < NPIX) {
#pragma unroll
      for (int s = 0; s < 4; ++s) {
        const size_t ko = (size_t)(jn + krow) * CH + (size_t)(kcb + 8 * s) * 8;
        rkh[s] = *(const short8*)(gkh + ko);
        rkl[s] = *(const short8*)(gkl + ko);
        rv[s]  = *(const short8*)(gv + (size_t)(s * 64 + w * 16 + (l >> 2)) * NPIX + jn + (l & 3) * 8);
      }
    }

    // ---- QK^T: 4 independent accumulator chains, 3-pass hi/lo ----
    f32x4 sa[2][2];
    sa[0][0] = (f32x4){0.f, 0.f, 0.f, 0.f};
    sa[0][1] = (f32x4){0.f, 0.f, 0.f, 0.f};
    sa[1][0] = (f32x4){0.f, 0.f, 0.f, 0.f};
    sa[1][1] = (f32x4){0.f, 0.f, 0.f, 0.f};
#pragma unroll
    for (int kc = 0; kc < 8; ++kc) {
      const int h = kc >> 2;
      int byte0 = (l15 * 512 + (kc * 32 + cbase) * 2) ^ ((l15 & 7) << 4);
      int byte1 = ((l15 + 16) * 512 + (kc * 32 + cbase) * 2) ^ ((l15 & 7) << 4);
      short8 bh0 = *(const short8*)((const char*)khs + byte0);
      short8 bh1 = *(const short8*)((const char*)khs + byte1);
      short8 bl0 = *(const short8*)((const char*)kls + byte0);
      short8 bl1 = *(const short8*)((const char*)kls + byte1);
      sa[h][0] = __builtin_amdgcn_mfma_f32_16x16x32_bf16(qfh[kc], bh0, sa[h][0], 0, 0, 0);
      sa[h][1] = __builtin_amdgcn_mfma_f32_16x16x32_bf16(qfh[kc], bh1, sa[h][1], 0, 0, 0);
      sa[h][0] = __builtin_amdgcn_mfma_f32_16x16x32_bf16(qfl[kc], bh0, sa[h][0], 0, 0, 0);
      sa[h][1] = __builtin_amdgcn_mfma_f32_16x16x32_bf16(qfl[kc], bh1, sa[h][1], 0, 0, 0);
      sa[h][0] = __builtin_amdgcn_mfma_f32_16x16x32_bf16(qfh[kc], bl0, sa[h][0], 0, 0, 0);
      sa[h][1] = __builtin_amdgcn_mfma_f32_16x16x32_bf16(qfh[kc], bl1, sa[h][1], 0, 0, 0);
    }
    f32x4 s0, s1;
#pragma unroll
    for (int r = 0; r < 4; ++r) { s0[r] = sa[0][0][r] + sa[1][0][r]; s1[r] = sa[0][1][r] + sa[1][1][r]; }

    // ---- online softmax (max only; sums via ones-MFMA) ----
    float scale[4], p0[4], p1[4];
#pragma unroll
    for (int r = 0; r < 4; ++r) {
      float tm = fmaxf(s0[r], s1[r]);
      tm = fmaxf(tm, __shfl_xor(tm, 1));
      tm = fmaxf(tm, __shfl_xor(tm, 2));
      tm = fmaxf(tm, __shfl_xor(tm, 4));
      tm = fmaxf(tm, __shfl_xor(tm, 8));
      if (tm > m_r[r] + 8.f) {        // T13 defer-rescale
        scale[r] = __expf(m_r[r] - tm);
        m_r[r] = tm;
      } else {
        scale[r] = 1.f;
      }
      p0[r] = __expf(s0[r] - m_r[r]);
      p1[r] = __expf(s1[r] - m_r[r]);
    }
    if (scale[0] != 1.f || scale[1] != 1.f || scale[2] != 1.f || scale[3] != 1.f) {
#pragma unroll
      for (int nt = 0; nt < 16; ++nt) {
        o[nt][0] *= scale[0];
        o[nt][1] *= scale[1];
        o[nt][2] *= scale[2];
        o[nt][3] *= scale[3];
      }
      o_l[0] *= scale[0]; o_l[1] *= scale[1];
      o_l[2] *= scale[2]; o_l[3] *= scale[3];
    }

    // ---- P -> LDS (bf16), then PV + ones-MFMA ----
#pragma unroll
    for (int r = 0; r < 4; ++r) {
      ps[w][q4 * 4 + r][l15]      = (short)f2bf(p0[r]);
      ps[w][q4 * 4 + r][l15 + 16] = (short)f2bf(p1[r]);
    }
    short8 pa = *(const short8*)&ps[w][l15][cbase];
    o_l = __builtin_amdgcn_mfma_f32_16x16x32_bf16(pa, onesf, o_l, 0, 0, 0);
#pragma unroll
    for (int nt = 0; nt < 16; ++nt) {
      short8 vv = *(const short8*)&vs[nt * 16 + l15][cbase];
      o[nt] = __builtin_amdgcn_mfma_f32_16x16x32_bf16(pa, vv, o[nt], 0, 0, 0);
    }
  }

  // ---- epilogue ----
  float inv[4];
#pragma unroll
  for (int r = 0; r < 4; ++r) inv[r] = 1.f / o_l[r];
  float* ob = out + (size_t)b * CH * NPIX + i0 + w * 16;
#pragma unroll
  for (int nt = 0; nt < 16; ++nt) {
    const int c = nt * 16 + l15;
#pragma unroll
    for (int r = 0; r < 4; ++r)
      ob[(size_t)c * NPIX + q4 * 4 + r] = o[nt][r] * inv[r];
  }
}

extern "C" void kernel_launch(void* const* d_in, const int* in_sizes, int n_in,
                              void* d_out, int out_size, void* d_ws, size_t ws_size,
                              hipStream_t stream) {
  const float* x  = (const float*)d_in[0];
  const float* wq = (const float*)d_in[1];
  const float* bq = (const float*)d_in[2];
  const float* wk = (const float*)d_in[3];
  const float* bk = (const float*)d_in[4];
  const float* wv = (const float*)d_in[5];
  const float* bv = (const float*)d_in[6];
  float* out = (float*)d_out;

  const size_t per = (size_t)BATCH * NPIX * CH;   // 8.4M elems
  short* qh = (short*)d_ws;
  short* ql = qh + per;
  short* kh = ql + per;
  short* kl = kh + per;
  short* vb = kl + per;                            // 5 x 16.8 MB = 84 MB
  float* wTq = (float*)(vb + per);
  float* wTk = wTq + 256 * 256;
  float* wTv = wTk + 256 * 256;                    // +0.75 MB

  transpose_w<<<dim3(4, 4, 3), 256, 0, stream>>>(wq, wk, wv, wTq, wTk, wTv);
  proj_fused<<<512, 256, 0, stream>>>(x, wTq, bq, wTk, bk, wTv, bv,
                                      qh, ql, kh, kl, vb);
  attn_kernel<<<512, 256, 0, stream>>>(qh, ql, kh, kl, vb, out);
}

// Round 6
// 680.086 us; speedup vs baseline: 5.9866x; 1.2158x over previous
//
#include <hip/hip_runtime.h>
#include <hip/hip_bf16.h>
#include <hip/hip_fp16.h>

// B=8, C=256, H=W=64, N=4096.
// v4b: fp16 everywhere. Q hi/lo fp16 x K single fp16 (2-pass QK), fp16 P/V.
//      global_load_lds staging + LDS double buffer (1 barrier/tile).
//      Projections via MFMA GEMM (W hi/lo fp16 stacked, K=512).
//      (v4 fix: no LDS pointer arrays -> offset arithmetic.)

#define BATCH 8
#define CH    256
#define NPIX  4096

typedef __attribute__((ext_vector_type(8))) short    short8;
typedef __attribute__((ext_vector_type(8))) _Float16 half8;
typedef __attribute__((ext_vector_type(4))) float    f32x4;

__device__ __forceinline__ short f2h_s(float v) {
  _Float16 h = (_Float16)v;
  return __builtin_bit_cast(short, h);
}

__device__ __forceinline__ void gload16(const void* g, void* lds) {
  __builtin_amdgcn_global_load_lds(
      (const __attribute__((address_space(1))) unsigned int*)g,
      (__attribute__((address_space(3))) unsigned int*)lds, 16, 0, 0);
}

// ---------------- prep: whl[m][o][0:256]=hi(w), [256:512]=lo(w) -------------
__global__ __launch_bounds__(256) void prep_whl(
    const float* __restrict__ wq, const float* __restrict__ wk,
    const float* __restrict__ wv, short* __restrict__ whl) {
  const int m = blockIdx.x >> 8;       // grid 768
  const int o = blockIdx.x & 255;
  const float* w = m == 0 ? wq : m == 1 ? wk : wv;
  const int t = threadIdx.x;           // t == c
  float v = w[o * 256 + t];
  _Float16 h = (_Float16)v;
  _Float16 lo = (_Float16)(v - (float)h);
  short* dst = whl + ((size_t)m * 256 + o) * 512;
  dst[t] = __builtin_bit_cast(short, h);
  dst[256 + t] = __builtin_bit_cast(short, lo);
}

// ---------------- transpose x: [B,C,N] f32 -> xT [B,N,C] fp16 ---------------
__global__ __launch_bounds__(256) void transpose_x(
    const float* __restrict__ x, short* __restrict__ xT) {
  __shared__ float tile[64][68];
  const int id = blockIdx.x;           // 8 * 64 * 4 = 2048
  const int b = id >> 8;
  const int r = id & 255;
  const int n0 = (r >> 2) * 64, c0 = (r & 3) * 64;
  const int t = threadIdx.x;
  const float* xb = x + (size_t)b * CH * NPIX;
#pragma unroll
  for (int pass = 0; pass < 4; ++pass) {
    int c = pass * 16 + (t >> 4);
    float4 v = *(const float4*)&xb[(size_t)(c0 + c) * NPIX + n0 + (t & 15) * 4];
    *(float4*)&tile[c][(t & 15) * 4] = v;
  }
  __syncthreads();
  const int px = t >> 2;
#pragma unroll
  for (int mi = 0; mi < 2; ++mi) {
    int m = (t & 3) + mi * 4;
    short8 hh;
#pragma unroll
    for (int e = 0; e < 8; ++e) hh[e] = f2h_s(tile[m * 8 + e][px]);
    *(short8*)&xT[((size_t)b * NPIX + n0 + px) * CH + c0 + m * 8] = hh;
  }
}

// ---------------- projection GEMM: out[px][o] = xT . W^T + b ----------------
// grid 1536 = 8 b x 3 which x 32 px-tiles x 2 o-tiles. 256 thr, 4 waves (M32).
__global__ __launch_bounds__(256) void proj_gemm(
    const short* __restrict__ xT, const short* __restrict__ whl,
    const float* __restrict__ bq, const float* __restrict__ bk,
    const float* __restrict__ bv,
    short* __restrict__ qh, short* __restrict__ ql,
    short* __restrict__ kh, short* __restrict__ vbuf) {
  __shared__ __align__(16) short smem[4 * 8192];   // 64KB: As dbuf + Bs dbuf

  const int id = blockIdx.x;
  const int b = id / 192;
  const int r = id % 192;
  const int which = r >> 6;
  const int r2 = r & 63;
  const int px0 = (r2 >> 1) * 128, o0 = (r2 & 1) * 128;
  const int t = threadIdx.x;
  const int w = t >> 6, l = t & 63;
  const int l15 = l & 15, q4 = l >> 4;

  const short* Asrc = xT + ((size_t)b * NPIX + px0) * CH;
  const short* Bsrc = whl + ((size_t)which * 256 + o0) * 512;

  const int srow = t >> 1;             // staging: 2 lanes per row
  const int scb = (t & 1) * 4;         // 4 chunks each

  f32x4 acc[2][8];
#pragma unroll
  for (int i = 0; i < 2; ++i)
#pragma unroll
    for (int j = 0; j < 8; ++j) acc[i][j] = (f32x4){0.f, 0.f, 0.f, 0.f};

  short8 ra[4], rb[4];
  // prologue: load step 0
#pragma unroll
  for (int i = 0; i < 4; ++i) {
    int c = scb + i;
    ra[i] = *(const short8*)&Asrc[(size_t)srow * CH + 0 + c * 8];
    rb[i] = *(const short8*)&Bsrc[(size_t)srow * 512 + 0 + c * 8];
  }

#pragma unroll 1
  for (int s = 0; s < 8; ++s) {
    const int cur = s & 1;
    short* Asb = smem + cur * 8192;
    short* Bsb = smem + 16384 + cur * 8192;
    // write staged regs (swizzled: chunk ^= row&7)
#pragma unroll
    for (int i = 0; i < 4; ++i) {
      int c = scb + i;
      int wb = srow * 128 + ((c ^ (srow & 7)) * 16);
      *(short8*)((char*)Asb + wb) = ra[i];
      *(short8*)((char*)Bsb + wb) = rb[i];
    }
    __syncthreads();
    // prefetch next step
    if (s < 7) {
      int sn = s + 1;
      const short* Ap = Asrc + (sn & 3) * 64;
      const short* Bp = Bsrc + sn * 64;
#pragma unroll
      for (int i = 0; i < 4; ++i) {
        int c = scb + i;
        ra[i] = *(const short8*)&Ap[(size_t)srow * CH + c * 8];
        rb[i] = *(const short8*)&Bp[(size_t)srow * 512 + c * 8];
      }
    }
    // compute
#pragma unroll
    for (int kk = 0; kk < 2; ++kk) {
      half8 a[2];
#pragma unroll
      for (int mb = 0; mb < 2; ++mb) {
        int row = w * 32 + mb * 16 + l15;
        int byte = row * 128 + (((kk * 4 + q4) ^ (l15 & 7)) * 16);
        a[mb] = *(const half8*)((const char*)Asb + byte);
      }
#pragma unroll
      for (int nb = 0; nb < 8; ++nb) {
        int row = nb * 16 + l15;
        int byte = row * 128 + (((kk * 4 + q4) ^ (l15 & 7)) * 16);
        half8 bf = *(const half8*)((const char*)Bsb + byte);
        acc[0][nb] = __builtin_amdgcn_mfma_f32_16x16x32_f16(a[0], bf, acc[0][nb], 0, 0, 0);
        acc[1][nb] = __builtin_amdgcn_mfma_f32_16x16x32_f16(a[1], bf, acc[1][nb], 0, 0, 0);
      }
    }
    __syncthreads();
  }

  // epilogue
  const float* bias = which == 0 ? bq : which == 1 ? bk : bv;
  if (which < 2) {
#pragma unroll
    for (int nb = 0; nb < 8; ++nb) {
      float bv_ = bias[o0 + nb * 16 + l15];
      int o = o0 + nb * 16 + l15;
#pragma unroll
      for (int mb = 0; mb < 2; ++mb) {
#pragma unroll
        for (int rr = 0; rr < 4; ++rr) {
          float v = acc[mb][nb][rr] + bv_;
          int px = px0 + w * 32 + mb * 16 + q4 * 4 + rr;
          size_t off = ((size_t)b * NPIX + px) * CH + o;
          _Float16 h = (_Float16)v;
          if (which == 0) {
            qh[off] = __builtin_bit_cast(short, h);
            ql[off] = f2h_s(v - (float)h);
          } else {
            kh[off] = __builtin_bit_cast(short, h);
          }
        }
      }
    }
  } else {
    // v: transpose through LDS -> [B,C,N] fp16
    short* lt = smem;                  // [128][136] = 34.8KB
    __syncthreads();
#pragma unroll
    for (int nb = 0; nb < 8; ++nb) {
      float bv_ = bias[o0 + nb * 16 + l15];
      int o = nb * 16 + l15;
#pragma unroll
      for (int mb = 0; mb < 2; ++mb) {
#pragma unroll
        for (int rr = 0; rr < 4; ++rr) {
          int px = w * 32 + mb * 16 + q4 * 4 + rr;
          lt[o * 136 + px] = f2h_s(acc[mb][nb][rr] + bv_);
        }
      }
    }
    __syncthreads();
    const int ot = t >> 1;
#pragma unroll
    for (int i = 0; i < 8; ++i) {
      int c = (t & 1) * 8 + i;
      short8 vv = *(const short8*)&lt[ot * 136 + c * 8];
      *(short8*)&vbuf[((size_t)b * CH + o0 + ot) * NPIX + px0 + c * 8] = vv;
    }
  }
}

// ---------------- attention (fp16 MFMA flash, gload_lds dbuf) ---------------
#define QBLK 64
#define KBLK 32

__global__ __launch_bounds__(256) void attn_kernel(
    const short* __restrict__ qh, const short* __restrict__ ql,
    const short* __restrict__ kh, const short* __restrict__ vb,
    float* __restrict__ out) {
  __shared__ __align__(16) short khs[2][KBLK * CH];   // 2 x 16KB, XOR-swizzled
  __shared__ __align__(16) short vs[2][CH * KBLK];    // 2 x 16KB, linear
  __shared__ __align__(16) short ps[4][16][40];       // 5KB fp16 P

  const int phys = blockIdx.x;
  const int lid  = (phys & 7) * 64 + (phys >> 3);     // XCD owns one batch
  const int b  = lid >> 6;
  const int i0 = (lid & 63) * QBLK;

  const int t = threadIdx.x;
  const int w = t >> 6, l = t & 63;
  const int l15 = l & 15, q4 = l >> 4, cbase = q4 * 8;

  // Q fragments hi/lo fp16
  half8 qfh[8], qfl[8];
  {
    const size_t qrow = (size_t)b * NPIX + i0 + w * 16 + l15;
    const short* ph = qh + qrow * CH + cbase;
    const short* pl = ql + qrow * CH + cbase;
#pragma unroll
    for (int kc = 0; kc < 8; ++kc) {
      qfh[kc] = *(const half8*)(ph + kc * 32);
      qfl[kc] = *(const half8*)(pl + kc * 32);
    }
  }

  f32x4 o[16];
#pragma unroll
  for (int i = 0; i < 16; ++i) o[i] = (f32x4){0.f, 0.f, 0.f, 0.f};
  f32x4 o_l = (f32x4){0.f, 0.f, 0.f, 0.f};
  float m_r[4] = {-1e30f, -1e30f, -1e30f, -1e30f};

  half8 onesh;
#pragma unroll
  for (int e = 0; e < 8; ++e) onesh[e] = (_Float16)1.0f;

  const short* gk = kh + (size_t)b * NPIX * CH;
  const short* gv = vb + (size_t)b * CH * NPIX;

  // stage tile j0 into buffer bn: wave issues 4 K + 4 V gload_lds (16B each)
  auto issue = [&](int j0, int bn) {
#pragma unroll
    for (int i = 0; i < 4; ++i) {
      const int ins = w * 4 + i;
      const int krow = ins * 2 + (l >> 5);
      const int kch = (l & 31) ^ (krow & 7);          // pre-swizzled source
      gload16(gk + ((size_t)(j0 + krow)) * CH + kch * 8,
              (short*)&khs[bn][0] + ins * 512);
      const int vch = ins * 16 + (l >> 2);
      gload16(gv + (size_t)vch * NPIX + j0 + (l & 3) * 8,
              (short*)&vs[bn][0] + ins * 512);
    }
  };

  issue(0, 0);

#pragma unroll 1
  for (int j0 = 0; j0 < NPIX; j0 += KBLK) {
    const int cur = (j0 >> 5) & 1;
    asm volatile("s_waitcnt vmcnt(0)" ::: "memory");
    __syncthreads();
    if (j0 + KBLK < NPIX) issue(j0 + KBLK, cur ^ 1);

    // ---- QK^T: 2-pass (qh + ql) x kh, 4 independent chains ----
    f32x4 s0h = (f32x4){0.f, 0.f, 0.f, 0.f}, s0l = s0h, s1h = s0h, s1l = s0h;
#pragma unroll
    for (int kc = 0; kc < 8; ++kc) {
      int byte0 = (l15 * 512 + (kc * 32 + cbase) * 2) ^ ((l15 & 7) << 4);
      int byte1 = ((l15 + 16) * 512 + (kc * 32 + cbase) * 2) ^ ((l15 & 7) << 4);
      half8 b0 = *(const half8*)((const char*)&khs[cur][0] + byte0);
      half8 b1 = *(const half8*)((const char*)&khs[cur][0] + byte1);
      s0h = __builtin_amdgcn_mfma_f32_16x16x32_f16(qfh[kc], b0, s0h, 0, 0, 0);
      s0l = __builtin_amdgcn_mfma_f32_16x16x32_f16(qfl[kc], b0, s0l, 0, 0, 0);
      s1h = __builtin_amdgcn_mfma_f32_16x16x32_f16(qfh[kc], b1, s1h, 0, 0, 0);
      s1l = __builtin_amdgcn_mfma_f32_16x16x32_f16(qfl[kc], b1, s1l, 0, 0, 0);
    }
    f32x4 s0, s1;
#pragma unroll
    for (int rr = 0; rr < 4; ++rr) { s0[rr] = s0h[rr] + s0l[rr]; s1[rr] = s1h[rr] + s1l[rr]; }

    // ---- online softmax (max only; sums via ones-MFMA) ----
    float scale[4], p0[4], p1[4];
#pragma unroll
    for (int rr = 0; rr < 4; ++rr) {
      float tm = fmaxf(s0[rr], s1[rr]);
      tm = fmaxf(tm, __shfl_xor(tm, 1));
      tm = fmaxf(tm, __shfl_xor(tm, 2));
      tm = fmaxf(tm, __shfl_xor(tm, 4));
      tm = fmaxf(tm, __shfl_xor(tm, 8));
      if (tm > m_r[rr] + 8.f) {       // T13 defer-rescale
        scale[rr] = __expf(m_r[rr] - tm);
        m_r[rr] = tm;
      } else {
        scale[rr] = 1.f;
      }
      p0[rr] = __expf(s0[rr] - m_r[rr]);
      p1[rr] = __expf(s1[rr] - m_r[rr]);
    }
    if (scale[0] != 1.f || scale[1] != 1.f || scale[2] != 1.f || scale[3] != 1.f) {
#pragma unroll
      for (int nt = 0; nt < 16; ++nt) {
        o[nt][0] *= scale[0]; o[nt][1] *= scale[1];
        o[nt][2] *= scale[2]; o[nt][3] *= scale[3];
      }
      o_l[0] *= scale[0]; o_l[1] *= scale[1];
      o_l[2] *= scale[2]; o_l[3] *= scale[3];
    }

    // ---- P (fp16) -> LDS, then PV + ones row-sums ----
#pragma unroll
    for (int rr = 0; rr < 4; ++rr) {
      ps[w][q4 * 4 + rr][l15]      = f2h_s(p0[rr]);
      ps[w][q4 * 4 + rr][l15 + 16] = f2h_s(p1[rr]);
    }
    half8 pa = *(const half8*)&ps[w][l15][cbase];
    o_l = __builtin_amdgcn_mfma_f32_16x16x32_f16(pa, onesh, o_l, 0, 0, 0);
#pragma unroll
    for (int nt = 0; nt < 16; ++nt) {
      half8 vv = *(const half8*)((const short*)&vs[cur][0] + (nt * 16 + l15) * 32 + cbase);
      o[nt] = __builtin_amdgcn_mfma_f32_16x16x32_f16(pa, vv, o[nt], 0, 0, 0);
    }
  }

  // ---- epilogue: out[b, c, i] = o / l ----
  float inv[4];
#pragma unroll
  for (int rr = 0; rr < 4; ++rr) inv[rr] = 1.f / o_l[rr];
  float* ob = out + (size_t)b * CH * NPIX + i0 + w * 16;
#pragma unroll
  for (int nt = 0; nt < 16; ++nt) {
    const int c = nt * 16 + l15;
#pragma unroll
    for (int rr = 0; rr < 4; ++rr)
      ob[(size_t)c * NPIX + q4 * 4 + rr] = o[nt][rr] * inv[rr];
  }
}

extern "C" void kernel_launch(void* const* d_in, const int* in_sizes, int n_in,
                              void* d_out, int out_size, void* d_ws, size_t ws_size,
                              hipStream_t stream) {
  const float* x  = (const float*)d_in[0];
  const float* wq = (const float*)d_in[1];
  const float* bq = (const float*)d_in[2];
  const float* wk = (const float*)d_in[3];
  const float* bk = (const float*)d_in[4];
  const float* wv = (const float*)d_in[5];
  const float* bv = (const float*)d_in[6];
  float* out = (float*)d_out;

  const size_t per = (size_t)BATCH * NPIX * CH;    // 8.39M elems
  short* xT  = (short*)d_ws;
  short* qhb = xT + per;
  short* qlb = qhb + per;
  short* khb = qlb + per;
  short* vbf = khb + per;                          // 5 x 16.8MB = 84MB
  short* whl = vbf + per;                          // + 0.79MB

  prep_whl<<<768, 256, 0, stream>>>(wq, wk, wv, whl);
  transpose_x<<<2048, 256, 0, stream>>>(x, xT);
  proj_gemm<<<1536, 256, 0, stream>>>(xT, whl, bq, bk, bv, qhb, qlb, khb, vbf);
  attn_kernel<<<512, 256, 0, stream>>>(qhb, qlb, khb, vbf, out);
}